// Round 4
// baseline (70.016 us; speedup 1.0000x reference)
//
#include <hip/hip_runtime.h>
#include <hip/hip_bf16.h>
#include <hip/hip_fp16.h>

#define NN 1024   // nodes
#define FD 64     // feature dim (in == out)
#define BB 32     // batch

typedef __attribute__((ext_vector_type(4))) float    f32x4;
typedef __attribute__((ext_vector_type(8))) _Float16 f16x8;

static __device__ __forceinline__ unsigned short f2hu(float x) {
  _Float16 h = (_Float16)x;
  return __builtin_bit_cast(unsigned short, h);
}
static __device__ __forceinline__ f16x8 bch(int4 v) {
  return __builtin_bit_cast(f16x8, v);
}

// ---------------- Kernel 01 (fused): k1-blocks (id%5==0) compute h=x@W, f, g, hF;
// compress-blocks pack adj (0/1 int32) into a 4MB bitmask laid out for k2's lanes.
// maskG layout: [b][rowGroup G=i>>4][lam=hi*16+(i&15)][8 u32]; word p covers tiles
// 2p,2p+1: byte0=a(2p) byte1=b(2p) byte2=a(2p+1) byte3=b(2p+1), where a=half0
// (j=t*64+hi*8+e), b=half1 (j=t*64+32+hi*8+e), bit e little-endian.
__global__ __launch_bounds__(256) void gat_k01(
    const float* __restrict__ x, const float* __restrict__ W,
    const float* __restrict__ av, const int* __restrict__ adj,
    float* __restrict__ fv, float* __restrict__ gv,
    unsigned short* __restrict__ hF, unsigned* __restrict__ maskG)
{
  __shared__ __align__(16) char smem[43008];
  const int tid = threadIdx.x;
  const int id  = blockIdx.x;

  if (id % 5 == 0) {
    // ================= k1 branch =================
    const int kb = id / 5;
    float*          Wl = (float*)smem;                          // 16384 B
    float*          xl = (float*)(smem + 16384);                // 17408 B (64x68)
    unsigned short* tl = (unsigned short*)(smem + 33792);       // 8192 B
    float*          al = (float*)(smem + 41984);                // 512 B

    const int b  = kb >> 4;
    const int n0 = (kb & 15) << 6;

    if (tid < 32) ((f32x4*)al)[tid] = ((const f32x4*)av)[tid];
    {
      const int r  = tid >> 2;
      const int cb = (tid & 3) << 2;
      const f32x4* Wg = (const f32x4*)W;
      const f32x4* xg = (const f32x4*)(x + ((size_t)(b * NN + n0)) * FD);
#pragma unroll
      for (int k = 0; k < 4; ++k) {
        f32x4 wv = Wg[r * 16 + cb + k];
        f32x4 xv = xg[r * 16 + cb + k];
        *(f32x4*)(Wl + r * FD + ((cb + k) << 2)) = wv;
        *(f32x4*)(xl + r * 68 + ((cb + k) << 2)) = xv;
      }
    }
    __syncthreads();

    const int r  = tid >> 2;
    const int o0 = (tid & 3) << 4;
    float acc[16];
#pragma unroll
    for (int i = 0; i < 16; ++i) acc[i] = 0.f;

#pragma unroll 8
    for (int f = 0; f < FD; ++f) {
      float xv = xl[r * 68 + f];
      const f32x4* wr = (const f32x4*)(Wl + f * FD + o0);
#pragma unroll
      for (int c = 0; c < 4; ++c) {
        f32x4 wv = wr[c];
        acc[c * 4 + 0] += xv * wv.x;
        acc[c * 4 + 1] += xv * wv.y;
        acc[c * 4 + 2] += xv * wv.z;
        acc[c * 4 + 3] += xv * wv.w;
      }
    }

    float fp = 0.f, gp = 0.f;
#pragma unroll
    for (int i = 0; i < 16; ++i) {
      fp += acc[i] * al[o0 + i];
      gp += acc[i] * al[FD + o0 + i];
    }
    fp += __shfl_xor(fp, 1); fp += __shfl_xor(fp, 2);
    gp += __shfl_xor(gp, 1); gp += __shfl_xor(gp, 2);
    if ((tid & 3) == 0) {
      fv[b * NN + n0 + r] = fp;
      gv[b * NN + n0 + r] = gp;
    }

#pragma unroll
    for (int i = 0; i < 16; ++i) {
      int o = o0 + i;
      tl[o * 64 + ((((r >> 3) ^ (o & 7)) << 3) | (r & 7))] = f2hu(acc[i]);
    }
    __syncthreads();
    {
      const int jt = n0 >> 6;
#pragma unroll
      for (int hh = 0; hh < 2; ++hh) {
        int u = tid + (hh << 8);
        int frag = u >> 6, l = u & 63;
        int o = ((frag >> 1) << 4) + (l & 15);
        int c = ((frag & 1) << 2) + (l >> 4);
        int4 v = *(const int4*)(tl + o * 64 + ((c ^ (o & 7)) << 3));
        *(int4*)(hF + ((((size_t)(b * 16 + jt)) * 8 + frag) * 64 + l) * 8) = v;
      }
    }
  } else {
    // ================= compress branch =================
    const int c  = id - id / 5 - 1;      // 0..2047
    unsigned* mbuf = (unsigned*)smem;    // 512 u32, layout lam + p*64
    const int b = c >> 6, G = c & 63;
    const int w = tid >> 6, l = tid & 63;
    const int rr = l >> 4, col16 = l & 15;
    const int row = G * 16 + w * 4 + rr;
    const int4* src = (const int4*)(adj + ((size_t)(b * NN + row)) * NN) + col16;

    int4 v[16];
#pragma unroll
    for (int q = 0; q < 16; ++q) v[q] = src[q * 16];

#pragma unroll
    for (int q = 0; q < 16; ++q) {
      int4 a = v[q];   // adj values are exactly {0,1}
      unsigned nib = (unsigned)a.x | ((unsigned)a.y << 1) |
                     ((unsigned)a.z << 2) | ((unsigned)a.w << 3);
      unsigned nb  = nib | ((unsigned)__shfl_xor((int)nib, 1) << 4);
      if (!(l & 1)) {   // even lane holds byte for j = q*64 + (l&15)*4 .. +7
        const int hi   = (l >> 1) & 3;
        const int half = (l >> 3) & 1;
        const int lam  = hi * 16 + w * 4 + rr;
        const int p    = q >> 1;
        const int bp   = (q & 1) * 2 + half;
        ((char*)smem)[(lam + p * 64) * 4 + bp] = (char)(nb & 0xff);
      }
    }
    __syncthreads();
    {
      const int lam = tid >> 2, p0 = (tid & 3) * 2;
      unsigned w0 = mbuf[lam + p0 * 64];
      unsigned w1 = mbuf[lam + p0 * 64 + 64];
      uint2 o; o.x = w0; o.y = w1;
      *(uint2*)(maskG + (((size_t)(b * 64 + G) * 64 + lam) * 8 + p0)) = o;
    }
  }
}

// ---------------- Kernel 2: masked-softmax attention + PV (MFMA f16) + elu
// Zero barriers in main loop; adjacency bits live in 8 per-lane registers;
// hF B-fragments double-buffered from L2.
__global__ __launch_bounds__(256) void gat_k2(
    const float* __restrict__ fv, const float* __restrict__ gv,
    const unsigned short* __restrict__ hF, const unsigned* __restrict__ maskG,
    float* __restrict__ out)
{
  __shared__ __align__(16) float gl[NN];
  __shared__ float red[4];

  const int tid  = threadIdx.x;
  const int b    = blockIdx.x >> 4;
  const int i0   = (blockIdx.x & 15) << 6;
  const int lane = tid & 63, w = tid >> 6;
  const int m16  = lane & 15, hi = lane >> 4;
  const int bN   = b * NN;

  // prologue: stage g, block shift Cb
  f32x4 g4 = *(const f32x4*)(gv + bN + tid * 4);
  *(f32x4*)(gl + tid * 4) = g4;
  float gm = fmaxf(fmaxf(g4.x, g4.y), fmaxf(g4.z, g4.w));
  float fm = fv[bN + i0 + lane];
#pragma unroll
  for (int m = 1; m < 64; m <<= 1) {
    gm = fmaxf(gm, __shfl_xor(gm, m));
    fm = fmaxf(fm, __shfl_xor(fm, m));
  }
  if (lane == 0) red[w] = gm;
  const float fr = fv[bN + i0 + w * 16 + m16];
  __syncthreads();
  gm = fmaxf(fmaxf(red[0], red[1]), fmaxf(red[2], red[3]));
  const float sm = fm + gm;
  const float Cb = fmaxf(sm, 0.2f * sm);  // >= max masked score

  // per-lane adjacency bits: 32B = 16 tiles x (a-byte, b-byte)
  const uint4* mp = (const uint4*)(maskG +
      ((size_t)(b * 64 + (blockIdx.x & 15) * 4 + w) * 64 + lane) * 8);
  const uint4 mA = mp[0], mB = mp[1];
  const unsigned mq[8] = {mA.x, mA.y, mA.z, mA.w, mB.x, mB.y, mB.z, mB.w};

  const int4* hFb = (const int4*)hF + (size_t)b * 8192 + lane;

  float dAcc = 0.f;
  f32x4 acc[4];
#pragma unroll
  for (int n = 0; n < 4; ++n) acc[n] = (f32x4){0.f, 0.f, 0.f, 0.f};

#define PCOMP(dst, bits, ga, gb) do {                                      \
    float e0 = fr + ga.x, e1 = fr + ga.y, e2 = fr + ga.z, e3 = fr + ga.w;  \
    float e4 = fr + gb.x, e5 = fr + gb.y, e6 = fr + gb.z, e7 = fr + gb.w;  \
    e0 = fmaxf(e0, 0.2f * e0) - Cb; e1 = fmaxf(e1, 0.2f * e1) - Cb;        \
    e2 = fmaxf(e2, 0.2f * e2) - Cb; e3 = fmaxf(e3, 0.2f * e3) - Cb;        \
    e4 = fmaxf(e4, 0.2f * e4) - Cb; e5 = fmaxf(e5, 0.2f * e5) - Cb;        \
    e6 = fmaxf(e6, 0.2f * e6) - Cb; e7 = fmaxf(e7, 0.2f * e7) - Cb;        \
    float p0 = (bits & 1u)   ? __expf(e0) : 0.f;                           \
    float p1 = (bits & 2u)   ? __expf(e1) : 0.f;                           \
    float p2 = (bits & 4u)   ? __expf(e2) : 0.f;                           \
    float p3 = (bits & 8u)   ? __expf(e3) : 0.f;                           \
    float p4 = (bits & 16u)  ? __expf(e4) : 0.f;                           \
    float p5 = (bits & 32u)  ? __expf(e5) : 0.f;                           \
    float p6 = (bits & 64u)  ? __expf(e6) : 0.f;                           \
    float p7 = (bits & 128u) ? __expf(e7) : 0.f;                           \
    dAcc += ((p0 + p1) + (p2 + p3)) + ((p4 + p5) + (p6 + p7));             \
    dst = (f16x8){(_Float16)p0, (_Float16)p1, (_Float16)p2, (_Float16)p3,  \
                  (_Float16)p4, (_Float16)p5, (_Float16)p6, (_Float16)p7}; \
  } while (0)

  int4 h[2][8];
#pragma unroll
  for (int k = 0; k < 8; ++k) h[0][k] = hFb[k * 64];

#pragma unroll
  for (int t = 0; t < 16; ++t) {
    const int cur = t & 1, nxt = cur ^ 1;
    if (t < 15) {                       // prefetch next tile's B-fragments
      const int4* hp = hFb + (size_t)(t + 1) * 512;
#pragma unroll
      for (int k = 0; k < 8; ++k) h[nxt][k] = hp[k * 64];
    }
    const unsigned mwrd = mq[t >> 1] >> ((t & 1) * 16);
    const unsigned ab = mwrd & 0xffu, bb = (mwrd >> 8) & 0xffu;
    const int jb = t * 64;
    f32x4 ga0 = *(const f32x4*)(gl + jb + hi * 8);
    f32x4 ga1 = *(const f32x4*)(gl + jb + hi * 8 + 4);
    f32x4 gb0 = *(const f32x4*)(gl + jb + 32 + hi * 8);
    f32x4 gb1 = *(const f32x4*)(gl + jb + 32 + hi * 8 + 4);
    f16x8 pa, pb;
    PCOMP(pa, ab, ga0, ga1);
    PCOMP(pb, bb, gb0, gb1);
    acc[0] = __builtin_amdgcn_mfma_f32_16x16x32_f16(pa, bch(h[cur][0]), acc[0], 0, 0, 0);
    acc[0] = __builtin_amdgcn_mfma_f32_16x16x32_f16(pb, bch(h[cur][1]), acc[0], 0, 0, 0);
    acc[1] = __builtin_amdgcn_mfma_f32_16x16x32_f16(pa, bch(h[cur][2]), acc[1], 0, 0, 0);
    acc[1] = __builtin_amdgcn_mfma_f32_16x16x32_f16(pb, bch(h[cur][3]), acc[1], 0, 0, 0);
    acc[2] = __builtin_amdgcn_mfma_f32_16x16x32_f16(pa, bch(h[cur][4]), acc[2], 0, 0, 0);
    acc[2] = __builtin_amdgcn_mfma_f32_16x16x32_f16(pb, bch(h[cur][5]), acc[2], 0, 0, 0);
    acc[3] = __builtin_amdgcn_mfma_f32_16x16x32_f16(pa, bch(h[cur][6]), acc[3], 0, 0, 0);
    acc[3] = __builtin_amdgcn_mfma_f32_16x16x32_f16(pb, bch(h[cur][7]), acc[3], 0, 0, 0);
  }
#undef PCOMP

  // denominator: combine the 4 hi-groups sharing each row
  dAcc += __shfl_xor(dAcc, 16);
  dAcc += __shfl_xor(dAcc, 32);

  float* outB = out + ((size_t)(bN + i0 + w * 16)) * FD;
#pragma unroll
  for (int rr = 0; rr < 4; ++rr) {
    const int lr = hi * 4 + rr;           // local row (C/D layout)
    float d   = __shfl(dAcc, lr);
    float inv = d > 0.f ? 1.f / d : 0.f;
#pragma unroll
    for (int n = 0; n < 4; ++n) {
      float v = acc[n][rr] * inv;
      v = v > 0.f ? v : (__expf(v) - 1.f);  // elu (alpha=1)
      outB[(size_t)lr * FD + n * 16 + m16] = v;
    }
  }
}

extern "C" void kernel_launch(void* const* d_in, const int* in_sizes, int n_in,
                              void* d_out, int out_size, void* d_ws, size_t ws_size,
                              hipStream_t stream) {
  const float* x   = (const float*)d_in[0];
  const int*   adj = (const int*)d_in[1];
  const float* W   = (const float*)d_in[2];
  const float* a   = (const float*)d_in[3];
  float* out = (float*)d_out;

  // workspace: hF (4MB) | fv (128KB) | gv (128KB) | maskG (4MB)
  unsigned short* hT = (unsigned short*)d_ws;
  float* fv = (float*)((char*)d_ws + (size_t)BB * FD * NN * 2);
  float* gv = fv + (size_t)BB * NN;
  unsigned* maskG = (unsigned*)(gv + (size_t)BB * NN);

  gat_k01<<<dim3(2560), dim3(256), 0, stream>>>(x, W, a, adj, fv, gv, hT, maskG);
  gat_k2<<<dim3(BB * 16), dim3(256), 0, stream>>>(fv, gv, hT, maskG, out);
}

// Round 5
// 60.018 us; speedup vs baseline: 1.1666x; 1.1666x over previous
//
#include <hip/hip_runtime.h>
#include <hip/hip_bf16.h>
#include <hip/hip_fp16.h>

#define NN 1024   // nodes
#define FD 64     // feature dim (in == out)
#define BB 32     // batch

typedef __attribute__((ext_vector_type(4))) float    f32x4;
typedef __attribute__((ext_vector_type(8))) _Float16 f16x8;
typedef __attribute__((ext_vector_type(4))) int      i32x4;

static __device__ __forceinline__ unsigned short f2hu(float x) {
  _Float16 h = (_Float16)x;
  return __builtin_bit_cast(unsigned short, h);
}
static __device__ __forceinline__ f16x8 bch(int4 v) {
  return __builtin_bit_cast(f16x8, v);
}

// ---------------- Kernel 1: h = x@W (fp32), f = h@a1, g = h@a2,
// hF = h^T in MFMA B-fragment order: unit ((b*16+jt)*8 + frag)*64 + lane,
// frag = n*2+kh holds h[o = n*16+(lane&15)][j = jt*64 + kh*32 + (lane>>4)*8 + e]
__global__ __launch_bounds__(256) void gat_k1(
    const float* __restrict__ x, const float* __restrict__ W,
    const float* __restrict__ av, float* __restrict__ fv,
    float* __restrict__ gv, unsigned short* __restrict__ hF)
{
  __shared__ __align__(16) float Wl[FD * FD];
  __shared__ __align__(16) float xl[FD * 68];
  __shared__ __align__(16) unsigned short tl[FD * 64];
  __shared__ __align__(16) float al[2 * FD];

  const int tid = threadIdx.x;
  const int b   = blockIdx.x >> 4;
  const int n0  = (blockIdx.x & 15) << 6;

  if (tid < 32) ((f32x4*)al)[tid] = ((const f32x4*)av)[tid];
  {
    const int r  = tid >> 2;
    const int cb = (tid & 3) << 2;
    const f32x4* Wg = (const f32x4*)W;
    const f32x4* xg = (const f32x4*)(x + ((size_t)(b * NN + n0)) * FD);
#pragma unroll
    for (int k = 0; k < 4; ++k) {
      f32x4 wv = Wg[r * 16 + cb + k];
      f32x4 xv = xg[r * 16 + cb + k];
      *(f32x4*)(Wl + r * FD + ((cb + k) << 2)) = wv;
      *(f32x4*)(xl + r * 68 + ((cb + k) << 2)) = xv;
    }
  }
  __syncthreads();

  const int r  = tid >> 2;          // row (local j) in tile
  const int o0 = (tid & 3) << 4;    // 16 output features
  float acc[16];
#pragma unroll
  for (int i = 0; i < 16; ++i) acc[i] = 0.f;

#pragma unroll 8
  for (int f = 0; f < FD; ++f) {
    float xv = xl[r * 68 + f];
    const f32x4* wr = (const f32x4*)(Wl + f * FD + o0);
#pragma unroll
    for (int c = 0; c < 4; ++c) {
      f32x4 wv = wr[c];
      acc[c * 4 + 0] += xv * wv.x;
      acc[c * 4 + 1] += xv * wv.y;
      acc[c * 4 + 2] += xv * wv.z;
      acc[c * 4 + 3] += xv * wv.w;
    }
  }

  float fp = 0.f, gp = 0.f;
#pragma unroll
  for (int i = 0; i < 16; ++i) {
    fp += acc[i] * al[o0 + i];
    gp += acc[i] * al[FD + o0 + i];
  }
  fp += __shfl_xor(fp, 1); fp += __shfl_xor(fp, 2);
  gp += __shfl_xor(gp, 1); gp += __shfl_xor(gp, 2);
  if ((tid & 3) == 0) {
    fv[b * NN + n0 + r] = fp;
    gv[b * NN + n0 + r] = gp;
  }

#pragma unroll
  for (int i = 0; i < 16; ++i) {
    int o = o0 + i;
    tl[o * 64 + ((((r >> 3) ^ (o & 7)) << 3) | (r & 7))] = f2hu(acc[i]);
  }
  __syncthreads();
  {
    const int jt = n0 >> 6;
#pragma unroll
    for (int hh = 0; hh < 2; ++hh) {
      int u = tid + (hh << 8);
      int frag = u >> 6, l = u & 63;
      int o = ((frag >> 1) << 4) + (l & 15);
      int c = ((frag & 1) << 2) + (l >> 4);
      int4 v = *(const int4*)(tl + o * 64 + ((c ^ (o & 7)) << 3));
      *(int4*)(hF + ((((size_t)(b * 16 + jt)) * 8 + frag) * 64 + l) * 8) = v;
    }
  }
}

// ---------------- Kernel 2: masked-softmax attention + PV (MFMA f16) + elu
// 2048 blocks (b x 16-row group), 4 waves split j (4 tiles each). Zero barriers
// in the main loop; adj nt-loaded (no L2 pollution); hF B-fragments from L2;
// one end barrier for cross-wave reduction.
__global__ __launch_bounds__(256) void gat_k2(
    const int* __restrict__ adj, const float* __restrict__ fv,
    const float* __restrict__ gv, const unsigned short* __restrict__ hF,
    float* __restrict__ out)
{
  __shared__ __align__(16) float gl[NN];      // 4 KB
  __shared__ float red[4];
  __shared__ __align__(16) float accb[4096];  // [w'][n][rr][lane] 16 KB
  __shared__ float dpart[4][16];

  const int tid  = threadIdx.x;
  const int b    = blockIdx.x >> 6;
  const int i0   = (blockIdx.x & 63) << 4;
  const int lane = tid & 63, w = tid >> 6;
  const int m16  = lane & 15, hi = lane >> 4;
  const int bN   = b * NN;

  // prologue: stage g, block shift Cb = lrelu(max f_rows + max g)
  f32x4 g4 = *(const f32x4*)(gv + bN + tid * 4);
  *(f32x4*)(gl + tid * 4) = g4;
  float gm = fmaxf(fmaxf(g4.x, g4.y), fmaxf(g4.z, g4.w));
#pragma unroll
  for (int m = 1; m < 64; m <<= 1) gm = fmaxf(gm, __shfl_xor(gm, m));
  if (lane == 0) red[w] = gm;
  const float fr = fv[bN + i0 + m16];
  float fm = fr;
#pragma unroll
  for (int m = 1; m < 16; m <<= 1) fm = fmaxf(fm, __shfl_xor(fm, m));
  __syncthreads();
  gm = fmaxf(fmaxf(red[0], red[1]), fmaxf(red[2], red[3]));
  const float sm = fm + gm;
  const float Cb = fmaxf(sm, 0.2f * sm);  // >= max masked score; p = exp(e-Cb) <= 1

  const int*  adjP = adj + ((size_t)(bN + i0 + m16)) * NN + w * 256 + hi * 8;
  const int4* hFb  = (const int4*)hF + (size_t)b * 8192 + lane;
  const int   w4   = w * 4;

  float dAcc = 0.f;
  f32x4 acc[4];
#pragma unroll
  for (int n = 0; n < 4; ++n) acc[n] = (f32x4){0.f, 0.f, 0.f, 0.f};

  i32x4 Aa0, Aa1, Aa2, Aa3, Ba0, Ba1, Ba2, Ba3;

#define LADJ(P, t) do { const int* p_ = adjP + ((t) << 6);       \
    P##0 = __builtin_nontemporal_load((const i32x4*)(p_));       \
    P##1 = __builtin_nontemporal_load((const i32x4*)(p_ + 4));   \
    P##2 = __builtin_nontemporal_load((const i32x4*)(p_ + 32));  \
    P##3 = __builtin_nontemporal_load((const i32x4*)(p_ + 36)); } while (0)

#define PCOMP(dst, ia, ib, ga, gb) do {                                    \
    float e0 = fr + ga.x, e1 = fr + ga.y, e2 = fr + ga.z, e3 = fr + ga.w;  \
    float e4 = fr + gb.x, e5 = fr + gb.y, e6 = fr + gb.z, e7 = fr + gb.w;  \
    e0 = fmaxf(e0, 0.2f * e0) - Cb; e1 = fmaxf(e1, 0.2f * e1) - Cb;        \
    e2 = fmaxf(e2, 0.2f * e2) - Cb; e3 = fmaxf(e3, 0.2f * e3) - Cb;        \
    e4 = fmaxf(e4, 0.2f * e4) - Cb; e5 = fmaxf(e5, 0.2f * e5) - Cb;        \
    e6 = fmaxf(e6, 0.2f * e6) - Cb; e7 = fmaxf(e7, 0.2f * e7) - Cb;        \
    float p0 = (ia.x > 0) ? __expf(e0) : 0.f;                              \
    float p1 = (ia.y > 0) ? __expf(e1) : 0.f;                              \
    float p2 = (ia.z > 0) ? __expf(e2) : 0.f;                              \
    float p3 = (ia.w > 0) ? __expf(e3) : 0.f;                              \
    float p4 = (ib.x > 0) ? __expf(e4) : 0.f;                              \
    float p5 = (ib.y > 0) ? __expf(e5) : 0.f;                              \
    float p6 = (ib.z > 0) ? __expf(e6) : 0.f;                              \
    float p7 = (ib.w > 0) ? __expf(e7) : 0.f;                              \
    dAcc += ((p0 + p1) + (p2 + p3)) + ((p4 + p5) + (p6 + p7));             \
    dst = (f16x8){(_Float16)p0, (_Float16)p1, (_Float16)p2, (_Float16)p3,  \
                  (_Float16)p4, (_Float16)p5, (_Float16)p6, (_Float16)p7}; \
  } while (0)

#define TILE(t, P) do {                                                    \
    const int jt_ = w4 + (t);                                              \
    const int4* hp_ = hFb + (size_t)jt_ * 512;                             \
    int4 h0_ = hp_[0],   h1_ = hp_[64],  h2_ = hp_[128], h3_ = hp_[192];   \
    int4 h4_ = hp_[256], h5_ = hp_[320], h6_ = hp_[384], h7_ = hp_[448];   \
    const float* gp_ = gl + jt_ * 64 + hi * 8;                             \
    f32x4 ga0_ = *(const f32x4*)(gp_);                                     \
    f32x4 ga1_ = *(const f32x4*)(gp_ + 4);                                 \
    f32x4 gc0_ = *(const f32x4*)(gp_ + 32);                                \
    f32x4 gc1_ = *(const f32x4*)(gp_ + 36);                                \
    f16x8 pa_, pb_;                                                        \
    PCOMP(pa_, P##0, P##1, ga0_, ga1_);                                    \
    PCOMP(pb_, P##2, P##3, gc0_, gc1_);                                    \
    acc[0] = __builtin_amdgcn_mfma_f32_16x16x32_f16(pa_, bch(h0_), acc[0], 0, 0, 0); \
    acc[0] = __builtin_amdgcn_mfma_f32_16x16x32_f16(pb_, bch(h1_), acc[0], 0, 0, 0); \
    acc[1] = __builtin_amdgcn_mfma_f32_16x16x32_f16(pa_, bch(h2_), acc[1], 0, 0, 0); \
    acc[1] = __builtin_amdgcn_mfma_f32_16x16x32_f16(pb_, bch(h3_), acc[1], 0, 0, 0); \
    acc[2] = __builtin_amdgcn_mfma_f32_16x16x32_f16(pa_, bch(h4_), acc[2], 0, 0, 0); \
    acc[2] = __builtin_amdgcn_mfma_f32_16x16x32_f16(pb_, bch(h5_), acc[2], 0, 0, 0); \
    acc[3] = __builtin_amdgcn_mfma_f32_16x16x32_f16(pa_, bch(h6_), acc[3], 0, 0, 0); \
    acc[3] = __builtin_amdgcn_mfma_f32_16x16x32_f16(pb_, bch(h7_), acc[3], 0, 0, 0); \
  } while (0)

  LADJ(Aa, 0); LADJ(Ba, 1);      // 2-tile-deep adj prefetch
  TILE(0, Aa); LADJ(Aa, 2);
  TILE(1, Ba); LADJ(Ba, 3);
  TILE(2, Aa);
  TILE(3, Ba);
#undef LADJ
#undef PCOMP
#undef TILE

  // per-wave denominator (row m16 over this wave's 256 cols)
  dAcc += __shfl_xor(dAcc, 16);
  dAcc += __shfl_xor(dAcc, 32);
  if (lane < 16) dpart[w][lane] = dAcc;

  // stash partial accumulators for cross-wave reduce
#pragma unroll
  for (int n = 0; n < 4; ++n)
#pragma unroll
    for (int rr = 0; rr < 4; ++rr)
      accb[((w * 4 + n) * 4 + rr) * 64 + lane] = acc[n][rr];
  __syncthreads();

  // wave w now owns feature chunk n = w; combine 4 partials, normalize, elu
  float* outB = out + ((size_t)(bN + i0)) * FD + w * 16 + m16;
#pragma unroll
  for (int rr = 0; rr < 4; ++rr) {
    const int lr = hi * 4 + rr;
    float d = dpart[0][lr] + dpart[1][lr] + dpart[2][lr] + dpart[3][lr];
    float inv = d > 0.f ? 1.f / d : 0.f;
    float v = (accb[((0 * 4 + w) * 4 + rr) * 64 + lane] +
               accb[((1 * 4 + w) * 4 + rr) * 64 + lane]) +
              (accb[((2 * 4 + w) * 4 + rr) * 64 + lane] +
               accb[((3 * 4 + w) * 4 + rr) * 64 + lane]);
    v *= inv;
    v = v > 0.f ? v : (__expf(v) - 1.f);   // elu (alpha=1)
    __builtin_nontemporal_store(v, outB + (size_t)lr * FD);
  }
}

extern "C" void kernel_launch(void* const* d_in, const int* in_sizes, int n_in,
                              void* d_out, int out_size, void* d_ws, size_t ws_size,
                              hipStream_t stream) {
  const float* x   = (const float*)d_in[0];
  const int*   adj = (const int*)d_in[1];
  const float* W   = (const float*)d_in[2];
  const float* a   = (const float*)d_in[3];
  float* out = (float*)d_out;

  // workspace: hF fp16 fragment-ordered (4 MB) | fv (128 KB) | gv (128 KB)
  unsigned short* hF = (unsigned short*)d_ws;
  float* fv = (float*)((char*)d_ws + (size_t)BB * FD * NN * 2);
  float* gv = fv + (size_t)BB * NN;

  gat_k1<<<dim3(BB * 16), dim3(256), 0, stream>>>(x, W, a, fv, gv, hF);
  gat_k2<<<dim3(BB * 64), dim3(256), 0, stream>>>(adj, fv, gv, hF, out);
}

// Round 6
// 59.146 us; speedup vs baseline: 1.1838x; 1.0148x over previous
//
#include <hip/hip_runtime.h>
#include <hip/hip_bf16.h>
#include <hip/hip_fp16.h>

#define NN 1024   // nodes
#define FD 64     // feature dim (in == out)
#define BB 32     // batch

typedef __attribute__((ext_vector_type(4))) float    f32x4;
typedef __attribute__((ext_vector_type(8))) _Float16 f16x8;
typedef __attribute__((ext_vector_type(4))) int      i32x4;

static __device__ __forceinline__ unsigned short f2hu(float x) {
  _Float16 h = (_Float16)x;
  return __builtin_bit_cast(unsigned short, h);
}
static __device__ __forceinline__ f16x8 bch(int4 v) {
  return __builtin_bit_cast(f16x8, v);
}

// ---------------- Kernel 1: h = x@W (fp32), f = h@a1, g = h@a2,
// hF = h^T in MFMA B-fragment order: unit ((b*16+jt)*8 + frag)*64 + lane,
// frag = n*2+kh holds h[o = n*16+(lane&15)][j = jt*64 + kh*32 + (lane>>4)*8 + e]
__global__ __launch_bounds__(256) void gat_k1(
    const float* __restrict__ x, const float* __restrict__ W,
    const float* __restrict__ av, float* __restrict__ fv,
    float* __restrict__ gv, unsigned short* __restrict__ hF)
{
  __shared__ __align__(16) float Wl[FD * FD];
  __shared__ __align__(16) float xl[FD * 68];
  __shared__ __align__(16) unsigned short tl[FD * 64];
  __shared__ __align__(16) float al[2 * FD];

  const int tid = threadIdx.x;
  const int b   = blockIdx.x >> 4;
  const int n0  = (blockIdx.x & 15) << 6;

  if (tid < 32) ((f32x4*)al)[tid] = ((const f32x4*)av)[tid];
  {
    const int r  = tid >> 2;
    const int cb = (tid & 3) << 2;
    const f32x4* Wg = (const f32x4*)W;
    const f32x4* xg = (const f32x4*)(x + ((size_t)(b * NN + n0)) * FD);
#pragma unroll
    for (int k = 0; k < 4; ++k) {
      f32x4 wv = Wg[r * 16 + cb + k];
      f32x4 xv = xg[r * 16 + cb + k];
      *(f32x4*)(Wl + r * FD + ((cb + k) << 2)) = wv;
      *(f32x4*)(xl + r * 68 + ((cb + k) << 2)) = xv;
    }
  }
  __syncthreads();

  const int r  = tid >> 2;          // row (local j) in tile
  const int o0 = (tid & 3) << 4;    // 16 output features
  float acc[16];
#pragma unroll
  for (int i = 0; i < 16; ++i) acc[i] = 0.f;

#pragma unroll 8
  for (int f = 0; f < FD; ++f) {
    float xv = xl[r * 68 + f];
    const f32x4* wr = (const f32x4*)(Wl + f * FD + o0);
#pragma unroll
    for (int c = 0; c < 4; ++c) {
      f32x4 wv = wr[c];
      acc[c * 4 + 0] += xv * wv.x;
      acc[c * 4 + 1] += xv * wv.y;
      acc[c * 4 + 2] += xv * wv.z;
      acc[c * 4 + 3] += xv * wv.w;
    }
  }

  float fp = 0.f, gp = 0.f;
#pragma unroll
  for (int i = 0; i < 16; ++i) {
    fp += acc[i] * al[o0 + i];
    gp += acc[i] * al[FD + o0 + i];
  }
  fp += __shfl_xor(fp, 1); fp += __shfl_xor(fp, 2);
  gp += __shfl_xor(gp, 1); gp += __shfl_xor(gp, 2);
  if ((tid & 3) == 0) {
    fv[b * NN + n0 + r] = fp;
    gv[b * NN + n0 + r] = gp;
  }

#pragma unroll
  for (int i = 0; i < 16; ++i) {
    int o = o0 + i;
    tl[o * 64 + ((((r >> 3) ^ (o & 7)) << 3) | (r & 7))] = f2hu(acc[i]);
  }
  __syncthreads();
  {
    const int jt = n0 >> 6;
#pragma unroll
    for (int hh = 0; hh < 2; ++hh) {
      int u = tid + (hh << 8);
      int frag = u >> 6, l = u & 63;
      int o = ((frag >> 1) << 4) + (l & 15);
      int c = ((frag & 1) << 2) + (l >> 4);
      int4 v = *(const int4*)(tl + o * 64 + ((c ^ (o & 7)) << 3));
      *(int4*)(hF + ((((size_t)(b * 16 + jt)) * 8 + frag) * 64 + l) * 8) = v;
    }
  }
}

// ---------------- Kernel 2: masked-softmax attention + PV (MFMA f16) + elu
// 512 blocks x 4 independent waves (16 rows x full j each). Zero main-loop
// barriers. BOTH adj and hF double-buffered in registers, issued 2 tiles
// ahead of consumption so every s_waitcnt is counted (never drains the
// pipeline): wait for H(t) leaves A(t+1),H(t+1),A(t+2) in flight.
__global__ __launch_bounds__(256, 2) void gat_k2(
    const int* __restrict__ adj, const float* __restrict__ fv,
    const float* __restrict__ gv, const unsigned short* __restrict__ hF,
    float* __restrict__ out)
{
  __shared__ __align__(16) float gl[NN];   // 4 KB
  __shared__ float red[4];

  const int tid  = threadIdx.x;
  const int b    = blockIdx.x >> 4;
  const int i0   = (blockIdx.x & 15) << 6;
  const int lane = tid & 63, w = tid >> 6;
  const int m16  = lane & 15, hi = lane >> 4;
  const int bN   = b * NN;

  // ---- prologue: stage g, block shift Cb = lrelu(max f_tile + max g)
  f32x4 g4 = *(const f32x4*)(gv + bN + tid * 4);
  *(f32x4*)(gl + tid * 4) = g4;
  float gm = fmaxf(fmaxf(g4.x, g4.y), fmaxf(g4.z, g4.w));
  float fm = fv[bN + i0 + lane];
#pragma unroll
  for (int m = 1; m < 64; m <<= 1) {
    gm = fmaxf(gm, __shfl_xor(gm, m));
    fm = fmaxf(fm, __shfl_xor(fm, m));
  }
  if (lane == 0) red[w] = gm;
  const float fr = fv[bN + i0 + w * 16 + m16];
  __syncthreads();
  gm = fmaxf(fmaxf(red[0], red[1]), fmaxf(red[2], red[3]));
  const float sm = fm + gm;
  const float Cb = fmaxf(sm, 0.2f * sm);  // >= max masked score; p = exp(e-Cb) <= 1

  const int*  adjP = adj + ((size_t)(bN + i0 + w * 16 + m16)) * NN + hi * 8;
  const int4* hFb  = (const int4*)hF + (size_t)b * 8192 + lane;

  float dAcc = 0.f;
  f32x4 acc[4];
#pragma unroll
  for (int n = 0; n < 4; ++n) acc[n] = (f32x4){0.f, 0.f, 0.f, 0.f};

  i32x4 A0_0, A0_1, A0_2, A0_3, A1_0, A1_1, A1_2, A1_3;
  int4  H0_0, H0_1, H0_2, H0_3, H0_4, H0_5, H0_6, H0_7;
  int4  H1_0, H1_1, H1_2, H1_3, H1_4, H1_5, H1_6, H1_7;

#define LADJ(P, t) do { const int* p_ = adjP + ((t) << 6);       \
    P##_0 = __builtin_nontemporal_load((const i32x4*)(p_));      \
    P##_1 = __builtin_nontemporal_load((const i32x4*)(p_ + 4));  \
    P##_2 = __builtin_nontemporal_load((const i32x4*)(p_ + 32)); \
    P##_3 = __builtin_nontemporal_load((const i32x4*)(p_ + 36)); } while (0)

#define LHF(P, t) do { const int4* hp_ = hFb + (size_t)(t) * 512; \
    P##_0 = hp_[0];   P##_1 = hp_[64];  P##_2 = hp_[128];         \
    P##_3 = hp_[192]; P##_4 = hp_[256]; P##_5 = hp_[320];         \
    P##_6 = hp_[384]; P##_7 = hp_[448]; } while (0)

#define PCOMP(dst, ia, ib, ga, gb) do {                                    \
    float e0 = fr + ga.x, e1 = fr + ga.y, e2 = fr + ga.z, e3 = fr + ga.w;  \
    float e4 = fr + gb.x, e5 = fr + gb.y, e6 = fr + gb.z, e7 = fr + gb.w;  \
    e0 = fmaxf(e0, 0.2f * e0) - Cb; e1 = fmaxf(e1, 0.2f * e1) - Cb;        \
    e2 = fmaxf(e2, 0.2f * e2) - Cb; e3 = fmaxf(e3, 0.2f * e3) - Cb;        \
    e4 = fmaxf(e4, 0.2f * e4) - Cb; e5 = fmaxf(e5, 0.2f * e5) - Cb;        \
    e6 = fmaxf(e6, 0.2f * e6) - Cb; e7 = fmaxf(e7, 0.2f * e7) - Cb;        \
    float p0 = (ia.x > 0) ? __expf(e0) : 0.f;                              \
    float p1 = (ia.y > 0) ? __expf(e1) : 0.f;                              \
    float p2 = (ia.z > 0) ? __expf(e2) : 0.f;                              \
    float p3 = (ia.w > 0) ? __expf(e3) : 0.f;                              \
    float p4 = (ib.x > 0) ? __expf(e4) : 0.f;                              \
    float p5 = (ib.y > 0) ? __expf(e5) : 0.f;                              \
    float p6 = (ib.z > 0) ? __expf(e6) : 0.f;                              \
    float p7 = (ib.w > 0) ? __expf(e7) : 0.f;                              \
    dAcc += ((p0 + p1) + (p2 + p3)) + ((p4 + p5) + (p6 + p7));             \
    dst = (f16x8){(_Float16)p0, (_Float16)p1, (_Float16)p2, (_Float16)p3,  \
                  (_Float16)p4, (_Float16)p5, (_Float16)p6, (_Float16)p7}; \
  } while (0)

  // STEP: consume tile t from (AP,HP); optionally issue t+2 into same bufs.
  // Order matters: PCOMP (frees AP) -> LADJ(t+2) -> MFMA (waits HP(t), which
  // is OLDER than the just-issued loads -> counted vmcnt) -> LHF(t+2).
#define STEP(t, AP, HP, PRE) do {                                          \
    const float* gp_ = gl + (t) * 64 + hi * 8;                             \
    f32x4 ga0_ = *(const f32x4*)(gp_);                                     \
    f32x4 ga1_ = *(const f32x4*)(gp_ + 4);                                 \
    f32x4 gb0_ = *(const f32x4*)(gp_ + 32);                                \
    f32x4 gb1_ = *(const f32x4*)(gp_ + 36);                                \
    f16x8 pa_, pb_;                                                        \
    PCOMP(pa_, AP##_0, AP##_1, ga0_, ga1_);                                \
    PCOMP(pb_, AP##_2, AP##_3, gb0_, gb1_);                                \
    if (PRE) LADJ(AP, (t) + 2);                                            \
    acc[0] = __builtin_amdgcn_mfma_f32_16x16x32_f16(pa_, bch(HP##_0), acc[0], 0, 0, 0); \
    acc[0] = __builtin_amdgcn_mfma_f32_16x16x32_f16(pb_, bch(HP##_1), acc[0], 0, 0, 0); \
    acc[1] = __builtin_amdgcn_mfma_f32_16x16x32_f16(pa_, bch(HP##_2), acc[1], 0, 0, 0); \
    acc[1] = __builtin_amdgcn_mfma_f32_16x16x32_f16(pb_, bch(HP##_3), acc[1], 0, 0, 0); \
    acc[2] = __builtin_amdgcn_mfma_f32_16x16x32_f16(pa_, bch(HP##_4), acc[2], 0, 0, 0); \
    acc[2] = __builtin_amdgcn_mfma_f32_16x16x32_f16(pb_, bch(HP##_5), acc[2], 0, 0, 0); \
    acc[3] = __builtin_amdgcn_mfma_f32_16x16x32_f16(pa_, bch(HP##_6), acc[3], 0, 0, 0); \
    acc[3] = __builtin_amdgcn_mfma_f32_16x16x32_f16(pb_, bch(HP##_7), acc[3], 0, 0, 0); \
    if (PRE) LHF(HP, (t) + 2);                                             \
  } while (0)

  LADJ(A0, 0); LHF(H0, 0);
  LADJ(A1, 1); LHF(H1, 1);

  STEP(0,  A0, H0, 1); STEP(1,  A1, H1, 1);
  STEP(2,  A0, H0, 1); STEP(3,  A1, H1, 1);
  STEP(4,  A0, H0, 1); STEP(5,  A1, H1, 1);
  STEP(6,  A0, H0, 1); STEP(7,  A1, H1, 1);
  STEP(8,  A0, H0, 1); STEP(9,  A1, H1, 1);
  STEP(10, A0, H0, 1); STEP(11, A1, H1, 1);
  STEP(12, A0, H0, 1); STEP(13, A1, H1, 1);
  STEP(14, A0, H0, 0); STEP(15, A1, H1, 0);

#undef LADJ
#undef LHF
#undef PCOMP
#undef STEP

  // denominator: combine the 4 hi-groups sharing each row (no LDS, no barrier)
  dAcc += __shfl_xor(dAcc, 16);
  dAcc += __shfl_xor(dAcc, 32);

  float* outB = out + ((size_t)(bN + i0 + w * 16)) * FD;
#pragma unroll
  for (int rr = 0; rr < 4; ++rr) {
    const int lr = hi * 4 + rr;           // local row (C/D layout)
    float d   = __shfl(dAcc, lr);
    float inv = d > 0.f ? 1.f / d : 0.f;
#pragma unroll
    for (int n = 0; n < 4; ++n) {
      float v = acc[n][rr] * inv;
      v = v > 0.f ? v : (__expf(v) - 1.f);  // elu (alpha=1)
      __builtin_nontemporal_store(v, outB + (size_t)lr * FD + n * 16 + m16);
    }
  }
}

extern "C" void kernel_launch(void* const* d_in, const int* in_sizes, int n_in,
                              void* d_out, int out_size, void* d_ws, size_t ws_size,
                              hipStream_t stream) {
  const float* x   = (const float*)d_in[0];
  const int*   adj = (const int*)d_in[1];
  const float* W   = (const float*)d_in[2];
  const float* a   = (const float*)d_in[3];
  float* out = (float*)d_out;

  // workspace: hF fp16 fragment-ordered (4 MB) | fv (128 KB) | gv (128 KB)
  unsigned short* hF = (unsigned short*)d_ws;
  float* fv = (float*)((char*)d_ws + (size_t)BB * FD * NN * 2);
  float* gv = fv + (size_t)BB * NN;

  gat_k1<<<dim3(BB * 16), dim3(256), 0, stream>>>(x, W, a, fv, gv, hF);
  gat_k2<<<dim3(BB * 16), dim3(256), 0, stream>>>(adj, fv, gv, hF, out);
}

// Round 7
// 44.581 us; speedup vs baseline: 1.5705x; 1.3267x over previous
//
#include <hip/hip_runtime.h>
#include <hip/hip_bf16.h>
#include <hip/hip_fp16.h>

#define NN 1024   // nodes
#define FD 64     // feature dim (in == out)
#define BB 32     // batch

typedef __attribute__((ext_vector_type(4))) float    f32x4;
typedef __attribute__((ext_vector_type(8))) _Float16 f16x8;

static __device__ __forceinline__ unsigned short f2hu(float x) {
  _Float16 h = (_Float16)x;
  return __builtin_bit_cast(unsigned short, h);
}

// ---------------- Kernel 1 (R2-proven): h = x@W fp32, f = h@a1, g = h@a2,
// hT fp16 o-major [B][FD][NN]
__global__ __launch_bounds__(256) void gat_k1(
    const float* __restrict__ x, const float* __restrict__ W,
    const float* __restrict__ av, float* __restrict__ fv,
    float* __restrict__ gv, unsigned short* __restrict__ hT)
{
  __shared__ __align__(16) float Wl[FD * FD];
  __shared__ __align__(16) float xl[FD * 68];
  __shared__ __align__(16) unsigned short tl[FD * FD];
  __shared__ __align__(16) float al[2 * FD];

  const int tid = threadIdx.x;
  const int b   = blockIdx.x >> 4;
  const int n0  = (blockIdx.x & 15) << 6;

  if (tid < 32) ((f32x4*)al)[tid] = ((const f32x4*)av)[tid];
  {
    const int r  = tid >> 2;
    const int cb = (tid & 3) << 2;
    const f32x4* Wg = (const f32x4*)W;
    const f32x4* xg = (const f32x4*)(x + ((size_t)(b * NN + n0)) * FD);
#pragma unroll
    for (int k = 0; k < 4; ++k) {
      f32x4 wv = Wg[r * 16 + cb + k];
      f32x4 xv = xg[r * 16 + cb + k];
      *(f32x4*)(Wl + r * FD + ((cb + k) << 2)) = wv;
      *(f32x4*)(xl + r * 68 + ((cb + k) << 2)) = xv;
    }
  }
  __syncthreads();

  const int r  = tid >> 2;
  const int o0 = (tid & 3) << 4;
  float acc[16];
#pragma unroll
  for (int i = 0; i < 16; ++i) acc[i] = 0.f;

#pragma unroll 8
  for (int f = 0; f < FD; ++f) {
    float xv = xl[r * 68 + f];
    const f32x4* wr = (const f32x4*)(Wl + f * FD + o0);
#pragma unroll
    for (int c = 0; c < 4; ++c) {
      f32x4 wv = wr[c];
      acc[c * 4 + 0] += xv * wv.x;
      acc[c * 4 + 1] += xv * wv.y;
      acc[c * 4 + 2] += xv * wv.z;
      acc[c * 4 + 3] += xv * wv.w;
    }
  }

  float fp = 0.f, gp = 0.f;
#pragma unroll
  for (int i = 0; i < 16; ++i) {
    fp += acc[i] * al[o0 + i];
    gp += acc[i] * al[FD + o0 + i];
  }
  fp += __shfl_xor(fp, 1); fp += __shfl_xor(fp, 2);
  gp += __shfl_xor(gp, 1); gp += __shfl_xor(gp, 2);
  if ((tid & 3) == 0) {
    fv[b * NN + n0 + r] = fp;
    gv[b * NN + n0 + r] = gp;
  }

#pragma unroll
  for (int i = 0; i < 16; ++i) {
    int o  = o0 + i;
    int sw = (o ^ (o >> 3)) & 7;
    tl[o * FD + ((((r >> 3) ^ sw) << 3) | (r & 7))] = f2hu(acc[i]);
  }
  __syncthreads();
  {
    const int c2 = tid & 7;
#pragma unroll
    for (int hh = 0; hh < 2; ++hh) {
      int o  = (tid >> 3) + 32 * hh;
      int sw = (o ^ (o >> 3)) & 7;
      f32x4 v = *(const f32x4*)(tl + o * FD + ((c2 ^ sw) << 3));
      *(f32x4*)(hT + ((size_t)(b * FD + o)) * NN + n0 + c2 * 8) = v;
    }
  }
}

// ---------------- Kernel 2: fused masked-softmax attention + PV (MFMA) + elu
// R2 structure (1024 blocks, 32-row i-tiles) with:
//  - raw s_barrier + lgkmcnt(0) (NO vmcnt drain -> global loads ride across)
//  - double-buffered Pl/Hl, ONE barrier per tile
//  - register prefetch distance 2 (counted vmcnt, never 0 in the loop)
//  - per-block staggered j-tile order (HBM channel spread)
__global__ __launch_bounds__(256) void gat_k2(
    const int* __restrict__ adj, const float* __restrict__ fv,
    const float* __restrict__ gv, const unsigned short* __restrict__ hT,
    float* __restrict__ out)
{
  __shared__ __align__(16) unsigned short Pl[2][32 * 64]; // 2 x 4 KB
  __shared__ __align__(16) unsigned short Hl[2][64 * 64]; // 2 x 8 KB
  __shared__ __align__(16) float gl[NN];                  // 4 KB
  __shared__ float dLds[32];
  __shared__ float red[8];

  const int tid  = threadIdx.x;
  const int b    = blockIdx.x >> 5;
  const int i0   = (blockIdx.x & 31) << 5;
  const int st   = blockIdx.x & 15;        // j-tile stagger
  const int lane = tid & 63, w = tid >> 6;
  const int q = tid >> 3, s = tid & 7;     // row q (0..31), col-chunk s (0..7)
  const int bN = b * NN;

  // ---- prologue: stage g, per-block shift Cb = lrelu(max f_tile + max g)
  f32x4 g4 = *(const f32x4*)(gv + bN + tid * 4);
  *(f32x4*)(gl + tid * 4) = g4;
  float gm = fmaxf(fmaxf(g4.x, g4.y), fmaxf(g4.z, g4.w));
  float fm = fv[bN + i0 + (tid & 31)];
#pragma unroll
  for (int m = 1; m < 64; m <<= 1) {
    gm = fmaxf(gm, __shfl_xor(gm, m));
    fm = fmaxf(fm, __shfl_xor(fm, m));
  }
  if (lane == 0) { red[w * 2] = gm; red[w * 2 + 1] = fm; }
  const float fr = fv[bN + i0 + q];
  __syncthreads();
  gm = fmaxf(fmaxf(red[0], red[2]), fmaxf(red[4], red[6]));
  fm = fmaxf(fmaxf(red[1], red[3]), fmaxf(red[5], red[7]));
  const float sm = fm + gm;
  const float Cb = fmaxf(sm, 0.2f * sm);   // >= max masked score; p <= 1

  const int*            adjS = adj + ((size_t)(bN + i0 + q)) * NN + s * 4;
  const unsigned short* hTS  = hT + ((size_t)(b * FD + q)) * NN + s * 8;

  float dAcc = 0.f;
  f32x4 acc[2];
  acc[0] = (f32x4){0.f, 0.f, 0.f, 0.f};
  acc[1] = (f32x4){0.f, 0.f, 0.f, 0.f};

  int4 Aa0, Aa1, Ah0, Ah1, Ba0, Ba1, Bh0, Bh1;

#define TLOAD(Ra0, Ra1, Rh0, Rh1, jt) do { const int j0_ = (jt) << 6; \
    Ra0 = *(const int4*)(adjS + j0_);                                 \
    Ra1 = *(const int4*)(adjS + j0_ + 32);                            \
    Rh0 = *(const int4*)(hTS + j0_);                                  \
    Rh1 = *(const int4*)(hTS + (size_t)32 * NN + j0_); } while (0)

#define PQUAD(avv, gg, half, p) do {                                       \
    float e0 = fr + gg.x; e0 = fmaxf(e0, 0.2f * e0) - Cb;                  \
    float e1 = fr + gg.y; e1 = fmaxf(e1, 0.2f * e1) - Cb;                  \
    float e2 = fr + gg.z; e2 = fmaxf(e2, 0.2f * e2) - Cb;                  \
    float e3 = fr + gg.w; e3 = fmaxf(e3, 0.2f * e3) - Cb;                  \
    float p0 = (avv.x > 0) ? __expf(e0) : 0.f;                             \
    float p1 = (avv.y > 0) ? __expf(e1) : 0.f;                             \
    float p2 = (avv.z > 0) ? __expf(e2) : 0.f;                             \
    float p3 = (avv.w > 0) ? __expf(e3) : 0.f;                             \
    dAcc += (p0 + p1) + (p2 + p3);                                         \
    uint2 uv_;                                                             \
    uv_.x = (unsigned)f2hu(p0) | ((unsigned)f2hu(p1) << 16);               \
    uv_.y = (unsigned)f2hu(p2) | ((unsigned)f2hu(p3) << 16);               \
    *(uint2*)(Pl[p] + q * 64 +                                             \
        (((((half) << 2) + (s >> 1)) ^ (q & 7)) << 3) + ((s & 1) << 2)) = uv_; \
  } while (0)

#define MSTEP(p) do {                                                      \
    const int m16_ = lane & 15, hi_ = lane >> 4;                           \
    const int ar_ = ((w & 1) << 4) + m16_;                                 \
    const f16x8 a0_ = *(const f16x8*)(Pl[p] + ar_ * 64 + (((hi_)     ^ (ar_ & 7)) << 3)); \
    const f16x8 a1_ = *(const f16x8*)(Pl[p] + ar_ * 64 + (((hi_ + 4) ^ (ar_ & 7)) << 3)); \
    _Pragma("unroll")                                                      \
    for (int n_ = 0; n_ < 2; ++n_) {                                       \
      const int o_ = ((w >> 1) << 5) + (n_ << 4) + m16_;                   \
      const f16x8 b0_ = *(const f16x8*)(Hl[p] + o_ * 64 + (((hi_)     ^ (o_ & 7)) << 3)); \
      const f16x8 b1_ = *(const f16x8*)(Hl[p] + o_ * 64 + (((hi_ + 4) ^ (o_ & 7)) << 3)); \
      acc[n_] = __builtin_amdgcn_mfma_f32_16x16x32_f16(a0_, b0_, acc[n_], 0, 0, 0);       \
      acc[n_] = __builtin_amdgcn_mfma_f32_16x16x32_f16(a1_, b1_, acc[n_], 0, 0, 0);       \
    }                                                                      \
  } while (0)

  // TILE_ONE: consume regs (tile t) -> LDS[p]; issue t+2 into same regs
  // (counted vmcnt: wait for t leaves t+1 in flight); lgkm drain; RAW
  // barrier (no vmcnt drain); MFMA from LDS[p].
#define TILE_ONE(t, Ra0, Ra1, Rh0, Rh1, p) do {                            \
    const int jt_ = ((t) + st) & 15;                                       \
    const int jg_ = jt_ << 6;                                              \
    f32x4 g0_ = *(const f32x4*)(gl + jg_ + s * 4);                         \
    f32x4 g1_ = *(const f32x4*)(gl + jg_ + 32 + s * 4);                    \
    PQUAD(Ra0, g0_, 0, p); PQUAD(Ra1, g1_, 1, p);                          \
    *(int4*)(Hl[p] + q * 64 + ((s ^ (q & 7)) << 3)) = Rh0;                 \
    *(int4*)(Hl[p] + (q + 32) * 64 + ((s ^ (q & 7)) << 3)) = Rh1;          \
    if ((t) + 2 < 16) TLOAD(Ra0, Ra1, Rh0, Rh1, (((t) + 2 + st) & 15));    \
    asm volatile("s_waitcnt lgkmcnt(0)" ::: "memory");                     \
    __builtin_amdgcn_s_barrier();                                          \
    MSTEP(p);                                                              \
  } while (0)

  TLOAD(Aa0, Aa1, Ah0, Ah1, st);
  TLOAD(Ba0, Ba1, Bh0, Bh1, (st + 1) & 15);
#pragma unroll
  for (int t = 0; t < 16; t += 2) {
    TILE_ONE(t,     Aa0, Aa1, Ah0, Ah1, 0);
    TILE_ONE(t + 1, Ba0, Ba1, Bh0, Bh1, 1);
  }
#undef TLOAD
#undef PQUAD
#undef MSTEP
#undef TILE_ONE

  // denominator: 8 threads (s=0..7) share row q
  dAcc += __shfl_xor(dAcc, 1);
  dAcc += __shfl_xor(dAcc, 2);
  dAcc += __shfl_xor(dAcc, 4);
  if (s == 0) dLds[q] = dAcc;
  __syncthreads();

  const int m16 = lane & 15, hi4 = lane >> 4;
  const int wr = (w & 1) << 4, wc = (w >> 1) << 5;
  float* outp = out + ((size_t)(bN + i0 + wr + hi4 * 4)) * FD + wc + m16;
#pragma unroll
  for (int rr = 0; rr < 4; ++rr) {
    float d   = dLds[wr + hi4 * 4 + rr];
    float inv = d > 0.f ? 1.f / d : 0.f;
#pragma unroll
    for (int n = 0; n < 2; ++n) {
      float v = acc[n][rr] * inv;
      v = v > 0.f ? v : (__expf(v) - 1.f);   // elu (alpha=1)
      outp[(size_t)rr * FD + n * 16] = v;
    }
  }
}

extern "C" void kernel_launch(void* const* d_in, const int* in_sizes, int n_in,
                              void* d_out, int out_size, void* d_ws, size_t ws_size,
                              hipStream_t stream) {
  const float* x   = (const float*)d_in[0];
  const int*   adj = (const int*)d_in[1];
  const float* W   = (const float*)d_in[2];
  const float* a   = (const float*)d_in[3];
  float* out = (float*)d_out;

  // workspace: hT fp16 [B][FD][NN] (4 MB) | f [B][NN] | g [B][NN]
  unsigned short* hT = (unsigned short*)d_ws;
  float* fv = (float*)((char*)d_ws + (size_t)BB * FD * NN * 2);
  float* gv = fv + (size_t)BB * NN;

  gat_k1<<<dim3(BB * 16), dim3(256), 0, stream>>>(x, W, a, fv, gv, hT);
  gat_k2<<<dim3(BB * 32), dim3(256), 0, stream>>>(adj, fv, gv, hT, out);
}